// Round 6
// baseline (356.473 us; speedup 1.0000x reference)
//
#include <hip/hip_runtime.h>

// LuGre friction cell, B=4096 x T=2048 serial steps, S=1, H=64.
// Round 11: dual-chain waves (2 sequences per 16-lane group).
//  - r10 result: issue-bound at 1 wave/SIMD (VALUBusy 77%, 152 cyc/step,
//    ~25 instr/step serving 4 seqs). Single chain can't fill its own 28-cyc
//    serial latency.
//  - New: each 16-lane group carries TWO sequences (two independent sz
//    chains per lane). Chains interleave -> latency bubbles filled; mkpre/
//    gather/x/store amortization per seq-step unchanged. 512 single-wave
//    blocks (2/CU). Per-wave per-step ~49 instr for 2 seq-steps ~= 98 cyc
//    -> predicted ~83 us vs 130.
//  - Payload broadcast still v_mov_dpp row_newbcast:t (VALU pipe, zero LDS).
//    DS pipe carries only the 1-per-16-steps table gather per seq.
//  - Per-step math / mkpre / gather / F bit-identical to r8/r9/r10.

#define DT 1e-3f
#define NV 256
#define VMINF (-6.6f)
#define VMAXF (6.6f)
#define ZAF   (2.56f)   // Chebyshev half-range in sz

// ---- stage 1: MLP node values + quartic solve -> global tabA/tabB ----------
__global__ __launch_bounds__(320) void coef_kernel(
    const float* __restrict__ W1,   // [2,64]
    const float* __restrict__ b1,   // [64]
    const float* __restrict__ W2,   // [64]
    const float* __restrict__ b2,   // [1]
    float4* __restrict__ tabA,      // [NV] (c0,c1,c2,c3) * -DT
    float*  __restrict__ tabB)      // [NV] c4 * -DT
{
    __shared__ float fsh[5];
    const int iv = blockIdx.x;          // v-node (256 blocks)
    const int j  = threadIdx.x >> 6;    // sz-node (5 waves/block)
    const int h  = threadIdx.x & 63;    // hidden unit
    const float v = VMINF + iv * ((VMAXF - VMINF) / (NV - 1));
    const float pn = 0.95105651629f * ZAF;   // cos(pi/10)*A
    const float qn = 0.58778525229f * ZAF;   // cos(3pi/10)*A
    const float szv = (j == 0) ? pn : (j == 1) ? -pn
                    : (j == 2) ? qn : (j == 3) ? -qn : 0.f;
    const float pre = fmaf(v, W1[h], fmaf(szv, W1[64 + h], b1[h]));
    float c = W2[h] * tanhf(pre);
#pragma unroll
    for (int o = 32; o; o >>= 1) c += __shfl_down(c, o);
    if (h == 0) {
        const float y = c + b2[0];
        fsh[j] = fmaxf(y, 0.f) + log1pf(expf(-fabsf(y)));  // softplus
    }
    __syncthreads();
    if (threadIdx.x == 0) {
        const float f0 = fsh[0], f1 = fsh[1], f2 = fsh[2], f3 = fsh[3];
        const float c0 = fsh[4];
        const float P = pn * pn, Q = qn * qn;
        const float ep = 0.5f * (f0 + f1) - c0;
        const float eq = 0.5f * (f2 + f3) - c0;
        const float op = 0.5f * (f0 - f1);
        const float oq = 0.5f * (f2 - f3);
        const float invPQ = 1.f / (P - Q);
        const float c4 = (ep / P - eq / Q) * invPQ;
        const float c2 = ep / P - c4 * P;
        const float c3 = (op / pn - oq / qn) * invPQ;
        const float c1 = op / pn - c3 * P;
        tabA[iv] = make_float4(-DT * c0, -DT * c1, -DT * c2, -DT * c3);
        tabB[iv] = -DT * c4;
    }
}

// broadcast lane L (0..15) of each 16-lane row to the whole row (VALU DPP16)
template <int L>
__device__ __forceinline__ float rb(float v) {
    const int s = __float_as_int(v);
    return __int_as_float(
        __builtin_amdgcn_update_dpp(s, s, 0x150 | L, 0xf, 0xf, false));
}

// ---- stage 2: main recurrence ----------------------------------------------
__global__ __launch_bounds__(64, 1) void lugre_kernel(
    const float* __restrict__ x,       // [B, T, 3]
    const float* __restrict__ sigma1,
    const float* __restrict__ sigma2,
    const float* __restrict__ alpha_p,
    const float* __restrict__ vs_p,
    const float4* __restrict__ tabA,   // [NV]
    const float*  __restrict__ tabB,   // [NV]
    float* __restrict__ out,           // [B, T]
    int B, int T)
{
    __shared__ float4 sA[NV];                       // 4096 B lerp table
    __shared__ float  sB[NV];                       // 1024 B

    const int tid = threadIdx.x;       // 64 threads = 1 wave
    for (int i = tid; i < NV; i += 64) { sA[i] = tabA[i]; sB[i] = tabB[i]; }

    const int lane16 = tid & 15;          // step owner within 16-lane group
    const int grp    = tid >> 4;          // 4 groups/wave, 2 seqs each
    const int sa     = blockIdx.x * 8 + grp * 2;   // first sequence
    const int NB     = T / 16;            // 128 blocks of 16 steps

    const float LOG2E = 1.4426950408889634f;
    const float s1v    = fabsf(sigma1[0]);
    const float s2v    = fabsf(sigma2[0]);
    const float s12    = s1v + s2v;
    const float alpha  = alpha_p[0];
    const float inv_vs = 1.0f / vs_p[0];
    const float SVC    = (NV - 1) / (VMAXF - VMINF);
    const float VOFF   = -VMINF * SVC;    // 127.5
    const float IMAX   = 254.999f;

    const float* __restrict__ pA = x + (size_t)sa * T * 3;
    const float* __restrict__ pB = pA + (size_t)T * 3;   // seq sa+1
    float* __restrict__ outA = out + (size_t)sa * T;
    float* __restrict__ outB = outA + T;

    // LDS lerp-table gather for one step's v (off the sz chain)
    auto gather = [&](float v, float4& A0, float4& A1,
                      float& B0, float& B1, float& fr) {
        const float fvr = __builtin_amdgcn_fmed3f(fmaf(v, SVC, VOFF), 0.f, IMAX);
        const float fvf = floorf(fvr);
        fr = fvr - fvf;
        const int iv = (int)fvf;
        A0 = sA[iv]; A1 = sA[iv + 1];
        B0 = sB[iv]; B1 = sB[iv + 1];
    };

    // mkpre for one step: lerp + premultiply -> payload in registers
    auto finish = [&](float v, float fc, float fs,
                      const float4& A0, const float4& A1,
                      float B0, float B1, float fr,
                      float& e0, float& e1, float& e2, float& e3, float& e4,
                      float& kk, float& ff, float& oQ, float& oSv) {
        const float av = fabsf(v);
        const float u  = av * inv_vs;
        const float lg = __builtin_amdgcn_logf(u);            // log2(u)
        const float pw = __builtin_amdgcn_exp2f(alpha * lg);  // u^alpha
        const float w_ = __builtin_amdgcn_exp2f(-LOG2E * pw); // exp(-u^alpha)
        const float g  = fmaf(fs - fc, w_, fc);
        kk = copysignf(g, v);
        const float avg = av * __builtin_amdgcn_rcpf(g);
        e0 = fmaf(fr, A1.x - A0.x, A0.x) * avg;
        e1 = fmaf(fr, A1.y - A0.y, A0.y) * avg;
        e2 = fmaf(fr, A1.z - A0.z, A0.z) * avg;
        e3 = fmaf(fr, A1.w - A0.w, A0.w) * avg;
        e4 = fmaf(fr, B1 - B0, B0) * avg;
        ff = fs;
        oQ  = -(s1v * avg);      // F = oQ*szn + (oSv + clip(szn))
        oSv = s12 * v;
    };

    // x queues (per seq): 1 = block n+1, 2 = block n+2 (state at top of iter n)
    float a1v, a1c, a1f, a2v, a2c, a2f;
    float b1v, b1c, b1f, b2v, b2c, b2f;
    // gather stage for block n+1 (consumed by this iter's finish)
    float4 gaA0, gaA1, gbA0, gbA1; float gaB0, gaB1, gafr, gbB0, gbB1, gbfr;
    // current payloads (block n): lane-own regs, row_newbcast at use
    float cae0, cae1, cae2, cae3, cae4, cak, caf, caQ, caSv;
    float cbe0, cbe1, cbe2, cbe3, cbe4, cbk, cbf, cbQ, cbSv;

    // prologue x loads (blocks 0..2, both seqs) before the barrier
    const int o0 = 3 * lane16;
    const float a0v = pA[o0], a0c = pA[o0 + 1], a0f = pA[o0 + 2];
    const float b0v = pB[o0], b0c = pB[o0 + 1], b0f = pB[o0 + 2];
    a1v = pA[48 + o0]; a1c = pA[48 + o0 + 1]; a1f = pA[48 + o0 + 2];
    b1v = pB[48 + o0]; b1c = pB[48 + o0 + 1]; b1f = pB[48 + o0 + 2];
    a2v = pA[96 + o0]; a2c = pA[96 + o0 + 1]; a2f = pA[96 + o0 + 2];
    b2v = pB[96 + o0]; b2c = pB[96 + o0 + 1]; b2f = pB[96 + o0 + 2];

    __syncthreads();                      // table resident

    {
        float4 tA0, tA1; float tB0, tB1, tfr;
        gather(a0v, tA0, tA1, tB0, tB1, tfr);
        finish(a0v, a0c, a0f, tA0, tA1, tB0, tB1, tfr,
               cae0, cae1, cae2, cae3, cae4, cak, caf, caQ, caSv);
        gather(b0v, tA0, tA1, tB0, tB1, tfr);
        finish(b0v, b0c, b0f, tA0, tA1, tB0, tB1, tfr,
               cbe0, cbe1, cbe2, cbe3, cbe4, cbk, cbf, cbQ, cbSv);
        gather(a1v, gaA0, gaA1, gaB0, gaB1, gafr);
        gather(b1v, gbA0, gbA1, gbB0, gbB1, gbfr);
    }

    float sza = 0.f, szb = 0.f;

#define CH(sz, e0, e1, e2, e3, e4, kk, ff, szn)                     \
        const float t1##szn = fmaf(e1, sz, e0);                     \
        const float t2##szn = fmaf(e3, sz, e2);                     \
        const float z2##szn = sz * sz;                              \
        const float sk##szn = sz - kk;                              \
        const float tt##szn = fmaf(t2##szn, z2##szn, t1##szn);      \
        const float z4##szn = z2##szn * z2##szn;                    \
        const float xd##szn = fmaf(e4, z4##szn, tt##szn);           \
        const float uu##szn = fmaf(xd##szn, 0.5f, 1.f);             \
        const float ww##szn = xd##szn * uu##szn;                    \
        const float szn     = fmaf(sk##szn, ww##szn, sz);           \
        sz = __builtin_amdgcn_fmed3f(szn, -ff, ff);

#define STEP(t) {                                                   \
        const float ae0 = rb<t>(cae0), ae1 = rb<t>(cae1);           \
        const float ae2 = rb<t>(cae2), ae3 = rb<t>(cae3);           \
        const float ae4 = rb<t>(cae4), akk = rb<t>(cak);            \
        const float aff = rb<t>(caf);                               \
        const float be0 = rb<t>(cbe0), be1 = rb<t>(cbe1);           \
        const float be2 = rb<t>(cbe2), be3 = rb<t>(cbe3);           \
        const float be4 = rb<t>(cbe4), bkk = rb<t>(cbk);            \
        const float bff = rb<t>(cbf);                               \
        CH(sza, ae0, ae1, ae2, ae3, ae4, akk, aff, szna##t)         \
        CH(szb, be0, be1, be2, be3, be4, bkk, bff, sznb##t)         \
        kepta = (lane16 == t) ? szna##t : kepta;                    \
        keptb = (lane16 == t) ? sznb##t : keptb; }

#pragma unroll 2
    for (int n = 0; n < NB; ++n) {
        // x load for block n+3 (~2 iterations of lead), both seqs
        const int bl = (n + 3 < NB) ? n + 3 : NB - 1;
        const int ox = 48 * bl + o0;
        const float lav = pA[ox], lac = pA[ox + 1], laf = pA[ox + 2];
        const float lbv = pB[ox], lbc = pB[ox + 1], lbf = pB[ox + 2];

        // table gathers for block n+2 (lane-own v resident in queue regs)
        float4 naA0, naA1, nbA0, nbA1;
        float  naB0, naB1, nafr, nbB0, nbB1, nbfr;
        gather(a2v, naA0, naA1, naB0, naB1, nafr);
        gather(b2v, nbA0, nbA1, nbB0, nbB1, nbfr);

        // mkpre for block n+1 -> next payloads (off the sz chains)
        float nae0, nae1, nae2, nae3, nae4, nak, naf, naQ, naSv;
        float nbe0, nbe1, nbe2, nbe3, nbe4, nbk, nbf, nbQ, nbSv;
        finish(a1v, a1c, a1f, gaA0, gaA1, gaB0, gaB1, gafr,
               nae0, nae1, nae2, nae3, nae4, nak, naf, naQ, naSv);
        finish(b1v, b1c, b1f, gbA0, gbA1, gbB0, gbB1, gbfr,
               nbe0, nbe1, nbe2, nbe3, nbe4, nbk, nbf, nbQ, nbSv);

        // 16 dual-chain steps on block n's payloads
        float kepta = 0.f, keptb = 0.f;
        STEP(0);  STEP(1);  STEP(2);  STEP(3);
        STEP(4);  STEP(5);  STEP(6);  STEP(7);
        STEP(8);  STEP(9);  STEP(10); STEP(11);
        STEP(12); STEP(13); STEP(14); STEP(15);

        // F for this lane's own step of block n (caf/cbf = lane-own fs)
        const float acl = __builtin_amdgcn_fmed3f(kepta, -caf, caf);
        outA[16 * n + lane16] = fmaf(caQ, kepta, caSv + acl);
        const float bcl = __builtin_amdgcn_fmed3f(keptb, -cbf, cbf);
        outB[16 * n + lane16] = fmaf(cbQ, keptb, cbSv + bcl);

        // rotate pipelines
        a1v = a2v; a1c = a2c; a1f = a2f;  a2v = lav; a2c = lac; a2f = laf;
        b1v = b2v; b1c = b2c; b1f = b2f;  b2v = lbv; b2c = lbc; b2f = lbf;
        gaA0 = naA0; gaA1 = naA1; gaB0 = naB0; gaB1 = naB1; gafr = nafr;
        gbA0 = nbA0; gbA1 = nbA1; gbB0 = nbB0; gbB1 = nbB1; gbfr = nbfr;
        cae0 = nae0; cae1 = nae1; cae2 = nae2; cae3 = nae3; cae4 = nae4;
        cak = nak; caf = naf; caQ = naQ; caSv = naSv;
        cbe0 = nbe0; cbe1 = nbe1; cbe2 = nbe2; cbe3 = nbe3; cbe4 = nbe4;
        cbk = nbk; cbf = nbf; cbQ = nbQ; cbSv = nbSv;
    }
#undef STEP
#undef CH
}

extern "C" void kernel_launch(void* const* d_in, const int* in_sizes, int n_in,
                              void* d_out, int out_size, void* d_ws, size_t ws_size,
                              hipStream_t stream) {
    const float* x  = (const float*)d_in[0];
    const float* s1 = (const float*)d_in[1];
    const float* s2 = (const float*)d_in[2];
    const float* al = (const float*)d_in[3];
    const float* vs = (const float*)d_in[4];
    const float* W1 = (const float*)d_in[5];
    const float* b1 = (const float*)d_in[6];
    const float* W2 = (const float*)d_in[7];
    const float* b2 = (const float*)d_in[8];
    float* out = (float*)d_out;

    float4* tabA = (float4*)d_ws;                       // 4096 B
    float*  tabB = (float*)((char*)d_ws + NV * 16);     // 1024 B

    const int T = 2048;
    const int B = out_size / T;               // 4096

    coef_kernel<<<NV, 320, 0, stream>>>(W1, b1, W2, b2, tabA, tabB);
    lugre_kernel<<<B / 8, 64, 0, stream>>>(x, s1, s2, al, vs, tabA, tabB,
                                           out, B, T);
}

// Round 7
// 250.813 us; speedup vs baseline: 1.4213x; 1.4213x over previous
//
#include <hip/hip_runtime.h>

// LuGre friction cell, B=4096 x T=2048 serial steps, S=1, H=64.
// Round 12: r10 shape + register-pipeline fences.
//  - r11 decode: VALUBusy is per-SIMD-averaged. r10 and r11 both run ~117
//    issue-cyc per wave-step on their busy SIMDs; r11 merely halved busy
//    SIMDs (512 waves -> 2/CU). 4 seqs/wave is the only shape that fills
//    all 1024 SIMDs with 4096 sequences -> r10 shape is forced.
//  - r9/r10/r11 all compiled to VGPR=36: the allocator collapsed the
//    declared software pipelines and rematerialized work (~2x issue waste:
//    117 cyc/wave-step measured vs ~50 static).
//  - New: every pipeline stage is a named scalar, pinned at loop bottom with
//    asm volatile("" : "+v"(x)). Loads/gathers must land in registers after
//    the 16-step chain (full latency cover), and cannot be sunk/re-issued.
//    x addressing via uniform scalar offset + constant lane offset.
//  - Math bit-identical to r8-r11 (same STEP/mkpre/gather/F).

#define DT 1e-3f
#define NV 256
#define VMINF (-6.6f)
#define VMAXF (6.6f)
#define ZAF   (2.56f)   // Chebyshev half-range in sz

// ---- stage 1: MLP node values + quartic solve -> global tabA/tabB ----------
__global__ __launch_bounds__(320) void coef_kernel(
    const float* __restrict__ W1,   // [2,64]
    const float* __restrict__ b1,   // [64]
    const float* __restrict__ W2,   // [64]
    const float* __restrict__ b2,   // [1]
    float4* __restrict__ tabA,      // [NV] (c0,c1,c2,c3) * -DT
    float*  __restrict__ tabB)      // [NV] c4 * -DT
{
    __shared__ float fsh[5];
    const int iv = blockIdx.x;          // v-node (256 blocks)
    const int j  = threadIdx.x >> 6;    // sz-node (5 waves/block)
    const int h  = threadIdx.x & 63;    // hidden unit
    const float v = VMINF + iv * ((VMAXF - VMINF) / (NV - 1));
    const float pn = 0.95105651629f * ZAF;   // cos(pi/10)*A
    const float qn = 0.58778525229f * ZAF;   // cos(3pi/10)*A
    const float szv = (j == 0) ? pn : (j == 1) ? -pn
                    : (j == 2) ? qn : (j == 3) ? -qn : 0.f;
    const float pre = fmaf(v, W1[h], fmaf(szv, W1[64 + h], b1[h]));
    float c = W2[h] * tanhf(pre);
#pragma unroll
    for (int o = 32; o; o >>= 1) c += __shfl_down(c, o);
    if (h == 0) {
        const float y = c + b2[0];
        fsh[j] = fmaxf(y, 0.f) + log1pf(expf(-fabsf(y)));  // softplus
    }
    __syncthreads();
    if (threadIdx.x == 0) {
        const float f0 = fsh[0], f1 = fsh[1], f2 = fsh[2], f3 = fsh[3];
        const float c0 = fsh[4];
        const float P = pn * pn, Q = qn * qn;
        const float ep = 0.5f * (f0 + f1) - c0;
        const float eq = 0.5f * (f2 + f3) - c0;
        const float op = 0.5f * (f0 - f1);
        const float oq = 0.5f * (f2 - f3);
        const float invPQ = 1.f / (P - Q);
        const float c4 = (ep / P - eq / Q) * invPQ;
        const float c2 = ep / P - c4 * P;
        const float c3 = (op / pn - oq / qn) * invPQ;
        const float c1 = op / pn - c3 * P;
        tabA[iv] = make_float4(-DT * c0, -DT * c1, -DT * c2, -DT * c3);
        tabB[iv] = -DT * c4;
    }
}

// broadcast lane L (0..15) of each 16-lane row to the whole row (VALU DPP16)
template <int L>
__device__ __forceinline__ float rb(float v) {
    const int s = __float_as_int(v);
    return __int_as_float(
        __builtin_amdgcn_update_dpp(s, s, 0x150 | L, 0xf, 0xf, false));
}

// pin a value into a live VGPR at this point (defeats sinking/remat)
#define KEEP(v) asm volatile("" : "+v"(v))

// ---- stage 2: main recurrence ----------------------------------------------
__global__ __launch_bounds__(256, 1) void lugre_kernel(
    const float* __restrict__ x,       // [B, T, 3]
    const float* __restrict__ sigma1,
    const float* __restrict__ sigma2,
    const float* __restrict__ alpha_p,
    const float* __restrict__ vs_p,
    const float4* __restrict__ tabA,   // [NV]
    const float*  __restrict__ tabB,   // [NV]
    float* __restrict__ out,           // [B, T]
    int B, int T)
{
    __shared__ float4 sA[NV];                       // 4096 B lerp table
    __shared__ float  sB[NV];                       // 1024 B

    const int tid = threadIdx.x;
    if (tid < NV) { sA[tid] = tabA[tid]; sB[tid] = tabB[tid]; }

    const int lane16 = tid & 15;          // step owner within 16-lane group
    const int grp    = (tid >> 4) & 3;    // 4 groups (sequences) per wave
    const int w      = tid >> 6;          // wave within block
    const int b      = blockIdx.x * 16 + w * 4 + grp;
    const int NB     = T / 16;            // 128 blocks of 16 steps

    const float LOG2E = 1.4426950408889634f;
    const float s1v    = fabsf(sigma1[0]);
    const float s2v    = fabsf(sigma2[0]);
    const float s12    = s1v + s2v;
    const float alpha  = alpha_p[0];
    const float inv_vs = 1.0f / vs_p[0];
    const float SVC    = (NV - 1) / (VMAXF - VMINF);
    const float VOFF   = -VMINF * SVC;    // 127.5
    const float IMAX   = 254.999f;

    const float* __restrict__ xb = x + (size_t)b * T * 3;
    float* __restrict__ outb = out + (size_t)b * T;
    const int o0 = 3 * lane16;

    // LDS lerp-table gather for one step's v (off the sz chain), scalar outs
    auto gather = [&](float v,
                      float& A0x, float& A0y, float& A0z, float& A0w,
                      float& A1x, float& A1y, float& A1z, float& A1w,
                      float& B0, float& B1, float& fr) {
        const float fvr = __builtin_amdgcn_fmed3f(fmaf(v, SVC, VOFF), 0.f, IMAX);
        const float fvf = floorf(fvr);
        fr = fvr - fvf;
        const int iv = (int)fvf;
        const float4 A0 = sA[iv], A1 = sA[iv + 1];
        A0x = A0.x; A0y = A0.y; A0z = A0.z; A0w = A0.w;
        A1x = A1.x; A1y = A1.y; A1z = A1.z; A1w = A1.w;
        B0 = sB[iv]; B1 = sB[iv + 1];
    };

    // mkpre for one step: lerp + premultiply -> payload in registers
    auto finish = [&](float v, float fc, float fs,
                      float A0x, float A0y, float A0z, float A0w,
                      float A1x, float A1y, float A1z, float A1w,
                      float B0, float B1, float fr,
                      float& e0, float& e1, float& e2, float& e3, float& e4,
                      float& kk, float& ff, float& oQ, float& oSv) {
        const float av = fabsf(v);
        const float u  = av * inv_vs;
        const float lg = __builtin_amdgcn_logf(u);            // log2(u)
        const float pw = __builtin_amdgcn_exp2f(alpha * lg);  // u^alpha
        const float w_ = __builtin_amdgcn_exp2f(-LOG2E * pw); // exp(-u^alpha)
        const float g  = fmaf(fs - fc, w_, fc);
        kk = copysignf(g, v);
        const float avg = av * __builtin_amdgcn_rcpf(g);
        e0 = fmaf(fr, A1x - A0x, A0x) * avg;
        e1 = fmaf(fr, A1y - A0y, A0y) * avg;
        e2 = fmaf(fr, A1z - A0z, A0z) * avg;
        e3 = fmaf(fr, A1w - A0w, A0w) * avg;
        e4 = fmaf(fr, B1 - B0, B0) * avg;
        ff = fs;
        oQ  = -(s1v * avg);      // F = oQ*szn + (oSv + clip(szn))
        oSv = s12 * v;
    };

    // x queues: xc = block n+1, xn = block n+2 (state at top of iter n)
    float xcv, xcc, xcf, xnv, xnc, xnf;
    // gather stage for block n+1 (consumed by this iter's finish)
    float gA0x, gA0y, gA0z, gA0w, gA1x, gA1y, gA1z, gA1w, gB0, gB1, gfr;
    // current payload (block n): lane-own regs, row_newbcast at use
    float ce0, ce1, ce2, ce3, ce4, ck, cf, cQ, cSv;

    // prologue: x for blocks 0..2 (before the barrier), then table-dependent
    const float a0v = xb[o0], a0c = xb[o0 + 1], a0f = xb[o0 + 2];
    xcv = xb[48 + o0]; xcc = xb[48 + o0 + 1]; xcf = xb[48 + o0 + 2];
    xnv = xb[96 + o0]; xnc = xb[96 + o0 + 1]; xnf = xb[96 + o0 + 2];

    __syncthreads();                      // table resident

    {
        float tA0x, tA0y, tA0z, tA0w, tA1x, tA1y, tA1z, tA1w, tB0, tB1, tfr;
        gather(a0v, tA0x, tA0y, tA0z, tA0w, tA1x, tA1y, tA1z, tA1w,
               tB0, tB1, tfr);
        finish(a0v, a0c, a0f, tA0x, tA0y, tA0z, tA0w, tA1x, tA1y, tA1z, tA1w,
               tB0, tB1, tfr, ce0, ce1, ce2, ce3, ce4, ck, cf, cQ, cSv);
        gather(xcv, gA0x, gA0y, gA0z, gA0w, gA1x, gA1y, gA1z, gA1w,
               gB0, gB1, gfr);
    }

    float sz = 0.f;

#define STEP(t) {                                                   \
        const float e0 = rb<t>(ce0), e1 = rb<t>(ce1);               \
        const float e2 = rb<t>(ce2), e3 = rb<t>(ce3);               \
        const float e4 = rb<t>(ce4), kk = rb<t>(ck), ff = rb<t>(cf);\
        const float t1  = fmaf(e1, sz, e0);                         \
        const float t2  = fmaf(e3, sz, e2);                         \
        const float z2  = sz * sz;                                  \
        const float smk = sz - kk;                                  \
        const float t12 = fmaf(t2, z2, t1);                         \
        const float z4  = z2 * z2;                                  \
        const float xd  = fmaf(e4, z4, t12);                        \
        const float u_  = fmaf(xd, 0.5f, 1.f);                      \
        const float w_  = xd * u_;                                  \
        const float szn = fmaf(smk, w_, sz);                        \
        sz = __builtin_amdgcn_fmed3f(szn, -ff, ff);                 \
        kept = (lane16 == t) ? szn : kept; }

#pragma unroll 2
    for (int n = 0; n < NB; ++n) {
        // x load for block n+3 (uniform scalar offset + constant lane offset)
        const int bl = (n + 3 < NB) ? n + 3 : NB - 1;
        const float* xp = xb + 48 * bl + o0;
        float lv = xp[0], lc = xp[1], lf = xp[2];

        // table gather for block n+2 (lane-own v resident in queue regs)
        float nA0x, nA0y, nA0z, nA0w, nA1x, nA1y, nA1z, nA1w, nB0, nB1, nfr;
        gather(xnv, nA0x, nA0y, nA0z, nA0w, nA1x, nA1y, nA1z, nA1w,
               nB0, nB1, nfr);

        // mkpre for block n+1 -> next payload (off the sz chain)
        float ne0, ne1, ne2, ne3, ne4, nk, nff, nQ, nSv;
        finish(xcv, xcc, xcf, gA0x, gA0y, gA0z, gA0w, gA1x, gA1y, gA1z, gA1w,
               gB0, gB1, gfr, ne0, ne1, ne2, ne3, ne4, nk, nff, nQ, nSv);

        // 16 chain steps on block n's payload (row_newbcast per step)
        float kept = 0.f;
        STEP(0);  STEP(1);  STEP(2);  STEP(3);
        STEP(4);  STEP(5);  STEP(6);  STEP(7);
        STEP(8);  STEP(9);  STEP(10); STEP(11);
        STEP(12); STEP(13); STEP(14); STEP(15);

        // F for this lane's own step of block n (cf = lane-own payload fs)
        const float cl = __builtin_amdgcn_fmed3f(kept, -cf, cf);
        outb[16 * n + lane16] = fmaf(cQ, kept, cSv + cl);

        // pin the whole next stage into registers HERE (after the chain):
        // waits drain with ~2000 cyc of cover; producers can't be sunk/remat.
        KEEP(lv);   KEEP(lc);   KEEP(lf);
        KEEP(nA0x); KEEP(nA0y); KEEP(nA0z); KEEP(nA0w);
        KEEP(nA1x); KEEP(nA1y); KEEP(nA1z); KEEP(nA1w);
        KEEP(nB0);  KEEP(nB1);  KEEP(nfr);
        KEEP(ne0);  KEEP(ne1);  KEEP(ne2);  KEEP(ne3);  KEEP(ne4);
        KEEP(nk);   KEEP(nff);  KEEP(nQ);   KEEP(nSv);

        // rotate pipelines
        xcv = xnv; xcc = xnc; xcf = xnf;
        xnv = lv;  xnc = lc;  xnf = lf;
        gA0x = nA0x; gA0y = nA0y; gA0z = nA0z; gA0w = nA0w;
        gA1x = nA1x; gA1y = nA1y; gA1z = nA1z; gA1w = nA1w;
        gB0 = nB0; gB1 = nB1; gfr = nfr;
        ce0 = ne0; ce1 = ne1; ce2 = ne2; ce3 = ne3; ce4 = ne4;
        ck = nk; cf = nff; cQ = nQ; cSv = nSv;
    }
#undef STEP
}

extern "C" void kernel_launch(void* const* d_in, const int* in_sizes, int n_in,
                              void* d_out, int out_size, void* d_ws, size_t ws_size,
                              hipStream_t stream) {
    const float* x  = (const float*)d_in[0];
    const float* s1 = (const float*)d_in[1];
    const float* s2 = (const float*)d_in[2];
    const float* al = (const float*)d_in[3];
    const float* vs = (const float*)d_in[4];
    const float* W1 = (const float*)d_in[5];
    const float* b1 = (const float*)d_in[6];
    const float* W2 = (const float*)d_in[7];
    const float* b2 = (const float*)d_in[8];
    float* out = (float*)d_out;

    float4* tabA = (float4*)d_ws;                       // 4096 B
    float*  tabB = (float*)((char*)d_ws + NV * 16);     // 1024 B

    const int T = 2048;
    const int B = out_size / T;               // 4096

    coef_kernel<<<NV, 320, 0, stream>>>(W1, b1, W2, b2, tabA, tabB);
    lugre_kernel<<<B / 16, 256, 0, stream>>>(x, s1, s2, al, vs, tabA, tabB,
                                             out, B, T);
}